// Round 2
// baseline (327.871 us; speedup 1.0000x reference)
//
#include <hip/hip_runtime.h>
#include <stdint.h>

// BMM: out[b,m,n] = round(alpha * sum_k a[b,m,k]*b[b,n,k]), int8 x int8 -> int32
// B=64, M=1024, N=1024, K=128.  Inputs arrive int32-expanded; output 256 MB int32.
//
// R6 = R5 resubmit (R5 hit an MI355X container infra failure; audit found no
// kernel-side hang/fault vector: barriers are convergent, all addresses
// in-bounds, no graph-capture violations).
//
// R5 theory: R2/R3/R4 all land ~155-160us kernel time despite a 4x read-traffic
// difference -> the shared write-path/epilogue is the binding constraint, not
// reads.  Two suspects, both fixed here:
//   (1) __syncthreads() makes the compiler emit `s_waitcnt vmcnt(0)` before
//       s_barrier (guide §5 barrier-drain) -> every epilogue round serializes
//       on nontemporal-store completion to DRAM (~900cy ack).  None of our
//       barriers needs vmcnt (they only protect LDS reuse), so all barriers
//       are now raw `s_waitcnt lgkmcnt(0); s_barrier` (m139/m201 pattern) and
//       stores stay fire-and-forget until s_endpgm.
//   (2) NT stores bypass L2/L3; their streaming rate is unverified (the 6.4TB/s
//       fill reference uses plain stores).  Output stores are now plain
//       dwordx4 (512B contiguous per half-wave -> full-line L2 write-back,
//       no RMW).  L3 protection of the 16.8MB packed set is not needed
//       (L3 = 256MB).
// Also: epilogue rounds widened 4x32 -> 2x64 rows (full 32KB slab, half the
// barriers), and staging loads hoisted ahead of the ds_writes for ILP.

typedef int v4i  __attribute__((ext_vector_type(4)));
typedef int v16i __attribute__((ext_vector_type(16)));

__device__ __forceinline__ int pack4(v4i w) {
    // low bytes of 4 int32 -> one dword of 4 int8 (two's complement)
    return (w.x & 0xFF) | ((w.y & 0xFF) << 8) | ((w.z & 0xFF) << 16) | (w.w << 24);
}

// Raw barrier: lgkm-only wait, NO vmcnt drain (unlike __syncthreads()).
// Correct here because barriers only order LDS producer/consumer phases;
// global stores are never read back.
__device__ __forceinline__ void lgkm_barrier() {
    asm volatile("s_waitcnt lgkmcnt(0)" ::: "memory");
    __builtin_amdgcn_s_barrier();
}

// ---- Pass 1: int32-expanded -> packed int8. 8.39M elems per tensor,
//      16 elems/thread, 2048 blocks x 256 threads.
__global__ __launch_bounds__(256) void prepack_kernel(
    const int* __restrict__ A, const int* __restrict__ Bm,
    uint8_t* __restrict__ Apk, uint8_t* __restrict__ Bpk)
{
    const int g = blockIdx.x * 256 + threadIdx.x;   // granule 0..524287
    const size_t eoff = (size_t)g * 16;             // int32 element offset

    v4i a[4], b[4];
#pragma unroll
    for (int i = 0; i < 4; ++i) {
        a[i] = __builtin_nontemporal_load((const v4i*)(A + eoff) + i);
        b[i] = __builtin_nontemporal_load((const v4i*)(Bm + eoff) + i);
    }
    v4i pa = { pack4(a[0]), pack4(a[1]), pack4(a[2]), pack4(a[3]) };
    v4i pb = { pack4(b[0]), pack4(b[1]), pack4(b[2]), pack4(b[3]) };
    *(v4i*)(Apk + eoff) = pa;   // plain stores: packed set is re-read 8x by BMM
    *(v4i*)(Bpk + eoff) = pb;
}

// ---- Pass 2: GEMM on packed int8. One 128x128 C-tile per block.
__global__ __launch_bounds__(256, 4) void bmm_s8s8_s32_kernel(
    const uint8_t* __restrict__ Apk,   // [64,1024,128] int8
    const uint8_t* __restrict__ Bpk,   // [64,1024,128] int8
    const float*   __restrict__ alpha_p,
    int*           __restrict__ out)   // [64,1024,1024]
{
    __shared__ uint8_t smem[32768];
    uint8_t* Als = smem;               // 16 KB, XOR-swizzled rows
    uint8_t* Bls = smem + 16384;       // 16 KB

    const int tid   = threadIdx.x;
    const int lane  = tid & 63;
    const int wave  = tid >> 6;        // 0..3
    const int half_ = lane >> 5;       // 0..1
    const int lrow  = lane & 31;       // 0..31

    const int bz = blockIdx.z;
    const int m0 = blockIdx.y << 7;
    const int n0 = blockIdx.x << 7;

    const float alpha = *alpha_p;

    // Packed tile bases (bytes); each 128-row tile is 16 KB contiguous.
    const size_t abase = ((size_t)bz * 1024 + (size_t)m0) * 128;
    const size_t bbase = ((size_t)bz * 1024 + (size_t)n0) * 128;

    // ---- Stage: 4 granules (16 B) per thread per matrix.  All 8 global
    //      loads issued first (ILP), then swizzled ds_writes:
    //      LDS[m][gp^(m&7)] = tile[m][gp].
    v4i pa[4], pb[4];
#pragma unroll
    for (int t = 0; t < 4; ++t) {
        const int G = t * 256 + tid;               // granule 0..1023
        pa[t] = *(const v4i*)(Apk + abase + (size_t)G * 16);
        pb[t] = *(const v4i*)(Bpk + bbase + (size_t)G * 16);
    }
#pragma unroll
    for (int t = 0; t < 4; ++t) {
        const int G  = t * 256 + tid;
        const int m  = G >> 3;
        const int gp = G & 7;
        const int loff = m * 128 + ((gp ^ (m & 7)) << 4);
        *(v4i*)(Als + loff) = pa[t];
        *(v4i*)(Bls + loff) = pb[t];
    }
    lgkm_barrier();   // ds_writes visible; no vmcnt drain needed (loads were
                      // consumed by the ds_writes, compiler waits per-wave)

    // ---- Compute: wave w -> cols w*32..+31, all 128 rows; 4 K-steps of 32.
    v16i acc[4] = {};
#pragma unroll
    for (int kk = 0; kk < 4; ++kk) {
        const int g = kk * 2 + half_;
        const int n = wave * 32 + lrow;
        const v4i bf = *(const v4i*)(Bls + n * 128 + ((g ^ (n & 7)) << 4));
        v4i af[4];
#pragma unroll
        for (int mi = 0; mi < 4; ++mi) {
            const int m = mi * 32 + lrow;
            af[mi] = *(const v4i*)(Als + m * 128 + ((g ^ (m & 7)) << 4));
        }
#pragma unroll
        for (int mi = 0; mi < 4; ++mi)
            acc[mi] = __builtin_amdgcn_mfma_i32_32x32x32_i8(af[mi], bf, acc[mi], 0, 0, 0);
    }
    lgkm_barrier();   // all fragment ds_reads done before LDS slab reuse

    // ---- Epilogue: 2 rounds of 64-row LDS transpose (full 32 KB slab) ->
    //      512B-per-half-wave plain dwordx4 stores.  No vmcnt drain anywhere:
    //      stores remain in flight across barriers until s_endpgm.
    //      C/D layout: col=lane&31, row=(r&3)+8*(r>>2)+4*(lane>>5).
    int* chunk = (int*)smem;           // 64 x 128 int32 slab
    int* outb  = out + ((size_t)bz << 20) + n0;

#pragma unroll
    for (int J = 0; J < 2; ++J) {
#pragma unroll
        for (int q = 0; q < 2; ++q) {
#pragma unroll
            for (int r = 0; r < 16; ++r) {
                const int row_local = q * 32 + (r & 3) + 8 * (r >> 2) + 4 * half_;
                chunk[row_local * 128 + wave * 32 + lrow] =
                    __float2int_rn((float)acc[2 * J + q][r] * alpha);
            }
        }
        lgkm_barrier();                // slab filled (lgkm only)
#pragma unroll
        for (int p = 0; p < 8; ++p) {
            const int row_local = p * 8 + (tid >> 5);       // 0..63
            const v4i v = *(const v4i*)((const uint8_t*)chunk + p * 4096 + tid * 16);
            *(v4i*)(outb + (size_t)(m0 + J * 64 + row_local) * 1024 + (tid & 31) * 4) = v;
        }
        if (J == 0) lgkm_barrier();    // slab reads done before round-1 writes
    }
}

extern "C" void kernel_launch(void* const* d_in, const int* in_sizes, int n_in,
                              void* d_out, int out_size, void* d_ws, size_t ws_size,
                              hipStream_t stream) {
    const int*   A     = (const int*)d_in[0];
    const int*   Bm    = (const int*)d_in[1];
    const float* alpha = (const float*)d_in[2];
    int*         out   = (int*)d_out;

    uint8_t* Apk = (uint8_t*)d_ws;                 // 8,388,608 B
    uint8_t* Bpk = (uint8_t*)d_ws + (8u << 20);    // 8,388,608 B

    prepack_kernel<<<dim3(2048), dim3(256), 0, stream>>>(A, Bm, Apk, Bpk);

    dim3 grid(8, 8, 64);   // n-tiles, m-tiles, batch
    bmm_s8s8_s32_kernel<<<grid, dim3(256), 0, stream>>>(Apk, Bpk, alpha, out);
}